// Round 10
// baseline (464.512 us; speedup 1.0000x reference)
//
#include <hip/hip_runtime.h>
#include <hip/hip_bf16.h>
#include <cstdint>
#include <cstddef>

// Established facts: inputs fp32, output fp32, ws >= ~69 MB usable.
// bf16 intermediates pass at absmax 0.0078 vs threshold 1.98e-2.
// r9 measured 377µs total; top kernel now attn_mfma 125µs:
//   MfmaUtil 11.7, VALU 25.5, HBM 4.2%, occ 27.7, BANK_CONFLICT 1.8e7.
//   -> LDS-throughput-bound + grid exactly 4 blocks/CU (vl imbalance).
// This round (attn only; GEMMs = r9 config):
//   - K direct global->reg (drop Ks LDS): K/head = 256KB, L2-hot across
//     q-tile blocks (m169 lesson). Removes 9 b128 DS ops/lane/tile.
//   - TQ 128->64, block 512->256: 2048 blocks = 8/CU for load balance
//     under vl imbalance; LDS 18.4KB/block fits 8 blocks/CU.

typedef __hip_bfloat16 bf16;
typedef unsigned short u16;
typedef __attribute__((ext_vector_type(8))) unsigned short ushort8_t;
typedef __attribute__((ext_vector_type(8))) __bf16 bf16x8;
typedef __attribute__((ext_vector_type(4))) float f32x4;

constexpr int Bn = 4, Sn = 2048, Dn = 1024, Hn = 16, HDn = 64;
constexpr size_t BSD = (size_t)Bn * Sn * Dn;     // 8,388,608
constexpr size_t DD  = (size_t)Dn * Dn;          // 1,048,576

__device__ __forceinline__ u16 f2b(float f) {
    union { bf16 h; u16 u; } c; c.h = __float2bfloat16(f); return c.u;
}

__device__ __forceinline__ bf16x8 cvt_bf8(f32x4 lo, f32x4 hi) {
    union { ushort8_t u; bf16x8 b; } c;
    c.u[0] = f2b(lo[0]); c.u[1] = f2b(lo[1]); c.u[2] = f2b(lo[2]); c.u[3] = f2b(lo[3]);
    c.u[4] = f2b(hi[0]); c.u[5] = f2b(hi[1]); c.u[6] = f2b(hi[2]); c.u[7] = f2b(hi[3]);
    return c.b;
}

// async global->LDS, 16B per lane. LDS dest = wave-uniform base + lane*16.
__device__ __forceinline__ void gl_lds16(const void* g, void* l) {
    __builtin_amdgcn_global_load_lds(
        (const __attribute__((address_space(1))) uint32_t*)g,
        (__attribute__((address_space(3))) uint32_t*)l, 16, 0, 0);
}

// ---------------------------------------------------------------------------
// W[K][N] fp32 -> Wt[N][K] bf16, 32x32 tiles. (unchanged)
// ---------------------------------------------------------------------------
__global__ __launch_bounds__(256) void transpose_w(
    const float* __restrict__ S0, const float* __restrict__ S1, const float* __restrict__ S2,
    u16* __restrict__ D0, u16* __restrict__ D1, u16* __restrict__ D2)
{
    __shared__ u16 tl[32][33];
    const int z = blockIdx.z;
    const float* S = (z == 0) ? S0 : ((z == 1) ? S1 : S2);
    u16*         D = (z == 0) ? D0 : ((z == 1) ? D1 : D2);
    const int k0 = blockIdx.y * 32, n0 = blockIdx.x * 32;
    const int t = threadIdx.x;
    const int r = t >> 3, c0 = (t & 7) * 4;
    float4 v = *(const float4*)(S + (size_t)(k0 + r) * Dn + n0 + c0);
    tl[r][c0] = f2b(v.x); tl[r][c0 + 1] = f2b(v.y);
    tl[r][c0 + 2] = f2b(v.z); tl[r][c0 + 3] = f2b(v.w);
    __syncthreads();
    ushort4 o;
    o.x = tl[c0][r]; o.y = tl[c0 + 1][r]; o.z = tl[c0 + 2][r]; o.w = tl[c0 + 3][r];
    *(ushort4*)(D + (size_t)(n0 + r) * Dn + k0 + c0) = o;
}

// ---------------------------------------------------------------------------
// QKV GEMM (r9 config, unchanged): dbuf, ds_read-first ordering.
// ---------------------------------------------------------------------------
__global__ __launch_bounds__(256) void gemm_qkv(
    const float* __restrict__ A0, const float* __restrict__ A1, const float* __restrict__ A2,
    const u16* __restrict__ B0, const u16* __restrict__ B1, const u16* __restrict__ B2,
    u16* __restrict__ C0, u16* __restrict__ C1, u16* __restrict__ C2, float qscale)
{
    constexpr int K = Dn, BK = 32, BM = 128, NT = K / BK;
    const int z = blockIdx.z;
    const float* A  = (z == 0) ? A0 : ((z == 1) ? A1 : A2);
    const u16*   Bt = (z == 0) ? B0 : ((z == 1) ? B1 : B2);
    u16*         C  = (z == 0) ? C0 : ((z == 1) ? C1 : C2);
    const float scale = (z == 0) ? qscale : 1.0f;

    __shared__ __attribute__((aligned(16))) float As32[2][BM][BK];  // 32 KB
    __shared__ __attribute__((aligned(16))) u16   Bs[2][BM][BK];    // 16 KB

    const int t = threadIdx.x, l = t & 63, w = t >> 6;
    const int i = l & 15, j = l >> 4;

    const int wl   = blockIdx.x * 64 + blockIdx.y;
    const int col0 = (wl & 7) * BM;
    const int row0 = (wl >> 3) * BM;
    const int m_off = (w & 1) * 64, n_off = (w >> 1) * 64;

    const size_t a_base = (size_t)(row0 + w * 32 + (l >> 3)) * K
                          + (size_t)(((l & 7) ^ (l >> 3)) * 4);
    const size_t b_base = (size_t)(col0 + w * 32 + (l >> 2)) * K
                          + (size_t)((l & 3) * 8);

    auto stage = [&](int buf, int kk) {
        float* al = &As32[buf][w * 32][0];
        u16*   bl = &Bs[buf][w * 32][0];
        #pragma unroll
        for (int c = 0; c < 4; c++)
            gl_lds16(A + a_base + (size_t)c * 8 * K + kk, al + c * 8 * BK);
        #pragma unroll
        for (int c = 0; c < 2; c++)
            gl_lds16(Bt + b_base + (size_t)c * 16 * K + kk, bl + c * 16 * BK);
    };

    f32x4 acc[4][4] = {};

    stage(0, 0);
    __syncthreads();

    #pragma unroll 2
    for (int kt = 0; kt < NT; kt++) {
        const int cur = kt & 1;

        f32x4 alo[4], ahi[4];
        bf16x8 bfr[4];
        const int xa = i & 7;
        #pragma unroll
        for (int mi = 0; mi < 4; mi++) {
            const float* rp = &As32[cur][m_off + mi * 16 + i][0];
            alo[mi] = *(const f32x4*)(rp + ((2 * j)     ^ xa) * 4);
            ahi[mi] = *(const f32x4*)(rp + ((2 * j + 1) ^ xa) * 4);
        }
        #pragma unroll
        for (int ni = 0; ni < 4; ni++)
            bfr[ni] = *(const bf16x8*)&Bs[cur][n_off + ni * 16 + i][j * 8];

        if (kt + 1 < NT) stage(cur ^ 1, (kt + 1) * BK);

        bf16x8 af[4];
        #pragma unroll
        for (int mi = 0; mi < 4; mi++)
            af[mi] = cvt_bf8(alo[mi], ahi[mi]);
        #pragma unroll
        for (int mi = 0; mi < 4; mi++)
            #pragma unroll
            for (int ni = 0; ni < 4; ni++)
                acc[mi][ni] = __builtin_amdgcn_mfma_f32_16x16x32_bf16(
                    af[mi], bfr[ni], acc[mi][ni], 0, 0, 0);

        __syncthreads();
    }

    #pragma unroll
    for (int mi = 0; mi < 4; mi++) {
        #pragma unroll
        for (int r = 0; r < 4; r++) {
            const int m = row0 + m_off + mi * 16 + j * 4 + r;
            const int b = m >> 11, s = m & (Sn - 1);
            #pragma unroll
            for (int ni = 0; ni < 4; ni++) {
                const int n = col0 + n_off + ni * 16 + i;
                const int h = n >> 6, hd = n & (HDn - 1);
                C[(((size_t)(b * Hn + h)) * Sn + s) * HDn + hd] = f2b(acc[mi][ni][r] * scale);
            }
        }
    }
}

// ---------------------------------------------------------------------------
// Output GEMM (r9 config, unchanged): dbuf, ds_read-first.
// ---------------------------------------------------------------------------
__global__ __launch_bounds__(256) void gemm_out(
    const u16* __restrict__ A, const u16* __restrict__ Bt, float* __restrict__ C)
{
    constexpr int K = Dn, BK = 32, BM = 128, NT = K / BK;
    __shared__ __attribute__((aligned(16))) u16 As[2][BM][BK];   // 16 KB
    __shared__ __attribute__((aligned(16))) u16 Bs[2][BM][BK];   // 16 KB

    const int t = threadIdx.x, l = t & 63, w = t >> 6;
    const int i = l & 15, j = l >> 4;
    const int wl   = blockIdx.x * 64 + blockIdx.y;
    const int col0 = (wl & 7) * BM;
    const int row0 = (wl >> 3) * BM;
    const int m_off = (w & 1) * 64, n_off = (w >> 1) * 64;

    const size_t a_base = (size_t)(row0 + w * 32 + (l >> 2)) * K + (size_t)((l & 3) * 8);
    const size_t b_base = (size_t)(col0 + w * 32 + (l >> 2)) * K + (size_t)((l & 3) * 8);

    auto stage = [&](int buf, int kk) {
        u16* al = &As[buf][w * 32][0];
        u16* bl = &Bs[buf][w * 32][0];
        #pragma unroll
        for (int c = 0; c < 2; c++)
            gl_lds16(A + a_base + (size_t)c * 16 * K + kk, al + c * 16 * BK);
        #pragma unroll
        for (int c = 0; c < 2; c++)
            gl_lds16(Bt + b_base + (size_t)c * 16 * K + kk, bl + c * 16 * BK);
    };

    f32x4 acc[4][4] = {};

    stage(0, 0);
    __syncthreads();

    #pragma unroll 2
    for (int kt = 0; kt < NT; kt++) {
        const int cur = kt & 1;

        bf16x8 af[4], bfr[4];
        #pragma unroll
        for (int mi = 0; mi < 4; mi++)
            af[mi] = *(const bf16x8*)&As[cur][m_off + mi * 16 + i][j * 8];
        #pragma unroll
        for (int ni = 0; ni < 4; ni++)
            bfr[ni] = *(const bf16x8*)&Bs[cur][n_off + ni * 16 + i][j * 8];

        if (kt + 1 < NT) stage(cur ^ 1, (kt + 1) * BK);

        #pragma unroll
        for (int mi = 0; mi < 4; mi++)
            #pragma unroll
            for (int ni = 0; ni < 4; ni++)
                acc[mi][ni] = __builtin_amdgcn_mfma_f32_16x16x32_bf16(
                    af[mi], bfr[ni], acc[mi][ni], 0, 0, 0);

        __syncthreads();
    }

    #pragma unroll
    for (int mi = 0; mi < 4; mi++) {
        #pragma unroll
        for (int r = 0; r < 4; r++) {
            const int m = row0 + m_off + mi * 16 + j * 4 + r;
            #pragma unroll
            for (int ni = 0; ni < 4; ni++) {
                const int n = col0 + n_off + ni * 16 + i;
                C[(size_t)m * Dn + n] = acc[mi][ni][r];
            }
        }
    }
}

// ---------------------------------------------------------------------------
// MFMA flash attention v2: TQ=64, 4 waves (256 thr), K direct global->reg
// (no Ks LDS). Vt (transposed V) and Ps remain in LDS.
// ---------------------------------------------------------------------------
__global__ __launch_bounds__(256) void attn_mfma(
    const u16* __restrict__ Qh, const u16* __restrict__ Kh, const u16* __restrict__ Vh,
    const int* __restrict__ vlen, u16* __restrict__ Out)
{
    constexpr int TQ = 64, TK = 64;
    __shared__ __attribute__((aligned(16))) u16 Vt[HDn][TK + 8];   // [64][72] d-major
    __shared__ __attribute__((aligned(16))) u16 Ps[TQ][TK + 8];    // [64][72]

    const int t = threadIdx.x, l = t & 63, w = t >> 6;   // w in [0,4)
    const int i = l & 15, j = l >> 4;

    const int b    = blockIdx.x & 3;            // interleave batches (vl imbalance)
    const int rest = blockIdx.x >> 2;
    const int h    = rest & 15;
    const int qt   = rest >> 4;                 // 0..31
    const int q0   = qt * TQ;
    const int vl   = vlen[b];

    const size_t hoff = ((size_t)(b * Hn + h)) * Sn * HDn;
    const u16* Qg = Qh + hoff + (size_t)q0 * HDn;
    const u16* Kg = Kh + hoff;
    const u16* Vg = Vh + hoff;

    // Q fragment: wave w owns q-rows [w*16, w*16+16). Q pre-scaled by 0.125.
    bf16x8 qf[2];
    #pragma unroll
    for (int ks = 0; ks < 2; ks++)
        qf[ks] = *(const bf16x8*)(Qg + (size_t)(w * 16 + i) * HDn + ks * 32 + j * 8);

    f32x4 acc_o[4] = {};
    float l_part[4] = {0.f, 0.f, 0.f, 0.f};

    const int ntiles = (vl + TK - 1) / TK;

    for (int kt = 0; kt < ntiles; kt++) {
        const int ks0 = kt * TK;
        __syncthreads();
        {   // stage V transposed: 256 thr, each 4 k-rows x 4 d-cols
            const int vr = (t >> 4) * 4, dc = (t & 15) * 4;
            ushort4 v0 = *(const ushort4*)(Vg + (size_t)(ks0 + vr) * HDn + dc);
            ushort4 v1 = *(const ushort4*)(Vg + (size_t)(ks0 + vr + 1) * HDn + dc);
            ushort4 v2 = *(const ushort4*)(Vg + (size_t)(ks0 + vr + 2) * HDn + dc);
            ushort4 v3 = *(const ushort4*)(Vg + (size_t)(ks0 + vr + 3) * HDn + dc);
            *(ushort2*)&Vt[dc + 0][vr]     = make_ushort2(v0.x, v1.x);
            *(ushort2*)&Vt[dc + 0][vr + 2] = make_ushort2(v2.x, v3.x);
            *(ushort2*)&Vt[dc + 1][vr]     = make_ushort2(v0.y, v1.y);
            *(ushort2*)&Vt[dc + 1][vr + 2] = make_ushort2(v2.y, v3.y);
            *(ushort2*)&Vt[dc + 2][vr]     = make_ushort2(v0.z, v1.z);
            *(ushort2*)&Vt[dc + 2][vr + 2] = make_ushort2(v2.z, v3.z);
            *(ushort2*)&Vt[dc + 3][vr]     = make_ushort2(v0.w, v1.w);
            *(ushort2*)&Vt[dc + 3][vr + 2] = make_ushort2(v2.w, v3.w);
        }
        __syncthreads();

        // ---- S = Q K^T : K fragments direct from global (L2-hot) ----
        f32x4 s[4] = {};
        #pragma unroll
        for (int ks = 0; ks < 2; ks++) {
            bf16x8 kf[4];
            #pragma unroll
            for (int ni = 0; ni < 4; ni++)
                kf[ni] = *(const bf16x8*)(Kg
                    + (size_t)(ks0 + ni * 16 + i) * HDn + ks * 32 + j * 8);
            #pragma unroll
            for (int ni = 0; ni < 4; ni++)
                s[ni] = __builtin_amdgcn_mfma_f32_16x16x32_bf16(
                    qf[ks], kf[ni], s[ni], 0, 0, 0);
        }

        // ---- p = exp(s) (no max), mask, accumulate l, spill P to LDS ----
        const bool tail = (ks0 + TK > vl);
        #pragma unroll
        for (int ni = 0; ni < 4; ni++) {
            const bool keep = !tail || (ks0 + ni * 16 + i < vl);
            #pragma unroll
            for (int r = 0; r < 4; r++) {
                float p = __expf(s[ni][r]);
                p = keep ? p : 0.0f;
                l_part[r] += p;
                // same-wave rows; DS ops in-order within a wave -> no barrier
                Ps[w * 16 + j * 4 + r][ni * 16 + i] = f2b(p);
            }
        }

        // ---- O += P V ----
        #pragma unroll
        for (int ks = 0; ks < 2; ks++) {
            bf16x8 pa = *(const bf16x8*)&Ps[w * 16 + i][ks * 32 + j * 8];
            bf16x8 vb[4];
            #pragma unroll
            for (int di = 0; di < 4; di++)
                vb[di] = *(const bf16x8*)&Vt[di * 16 + i][ks * 32 + j * 8];
            #pragma unroll
            for (int di = 0; di < 4; di++)
                acc_o[di] = __builtin_amdgcn_mfma_f32_16x16x32_bf16(
                    pa, vb[di], acc_o[di], 0, 0, 0);
        }
    }

    // ---- one-time l reduction across the 16 i-lanes ----
    #pragma unroll
    for (int r = 0; r < 4; r++) {
        float v = l_part[r];
        #pragma unroll
        for (int d = 1; d < 16; d <<= 1) v += __shfl_xor(v, d, 64);
        l_part[r] = v;
    }

    // ---- epilogue: merge heads into [B,S,D] bf16 ----
    #pragma unroll
    for (int r = 0; r < 4; r++) {
        const int q = q0 + w * 16 + j * 4 + r;
        const float inv = 1.0f / l_part[r];
        #pragma unroll
        for (int di = 0; di < 4; di++) {
            const int d = di * 16 + i;
            Out[((size_t)b * Sn + q) * Dn + h * HDn + d] = f2b(acc_o[di][r] * inv);
        }
    }
}

// ===========================================================================
extern "C" void kernel_launch(void* const* d_in, const int* in_sizes, int n_in,
                              void* d_out, int out_size, void* d_ws, size_t ws_size,
                              hipStream_t stream)
{
    const float* xq = (const float*)d_in[0];
    const float* xk = (const float*)d_in[1];
    const float* xv = (const float*)d_in[2];
    const int*   vl = (const int*)d_in[3];
    const float* Wq = (const float*)d_in[4];
    const float* Wk = (const float*)d_in[5];
    const float* Wv = (const float*)d_in[6];
    const float* Wo = (const float*)d_in[7];
    float* out = (float*)d_out;

    // scratch (all bf16): Qh|Kh|Vh|Ao = 4*BSD u16 = 67.1 MB.
    // WtQ/K/V live in the not-yet-written Ao region; WoT in dead Qh.
    u16* Qh = (u16*)d_ws;
    u16* Kh = Qh + BSD;
    u16* Vh = Kh + BSD;
    u16* Ao = Vh + BSD;
    u16* WtQ = Ao;
    u16* WtK = WtQ + DD;
    u16* WtV = WtK + DD;
    u16* WoT = Qh;

    transpose_w<<<dim3(32, 32, 3), 256, 0, stream>>>(Wq, Wk, Wv, WtQ, WtK, WtV);
    gemm_qkv<<<dim3(8, 64, 3), 256, 0, stream>>>(xq, xk, xv, WtQ, WtK, WtV,
                                                 Qh, Kh, Vh, 0.125f);
    attn_mfma<<<dim3(Bn * Hn * (Sn / 64)), 256, 0, stream>>>(Qh, Kh, Vh, vl, Ao);
    transpose_w<<<dim3(32, 32, 1), 256, 0, stream>>>(Wo, Wo, Wo, WoT, WoT, WoT);
    gemm_out<<<dim3(8, 64), 256, 0, stream>>>(Ao, WoT, out);
}

// Round 11
// 369.432 us; speedup vs baseline: 1.2574x; 1.2574x over previous
//
#include <hip/hip_runtime.h>
#include <hip/hip_bf16.h>
#include <cstdint>
#include <cstddef>

// Established facts: inputs fp32, output fp32, ws >= ~69 MB usable.
// bf16 intermediates pass at absmax 0.0078 vs threshold 1.98e-2.
// r9 = BEST measured: 377µs total (attn 125µs: Mfma 11.7, VALU 25.5,
//   HBM 4.2%, conflicts 1.8e7 -> LDS-bound; gemm_qkv no longer top-5).
// r10 (TQ=64 + K-from-global) REGRESSED to 464µs: doubled V-staging
//   work/conflicts + serial L2 latency in QK^T. Reverted.
// This round: r9 + ONE change — V-transpose staging re-mapped so each
//   thread owns one (d-row, 8-k chunk): 8 coalesced u16 global reads
//   (per-kk a wave reads one contiguous 128B V row) + ONE ushort8 LDS
//   write, replacing 8x ~8-way-conflicted ushort2 writes + pack VALU.

typedef __hip_bfloat16 bf16;
typedef unsigned short u16;
typedef __attribute__((ext_vector_type(8))) unsigned short ushort8_t;
typedef __attribute__((ext_vector_type(8))) __bf16 bf16x8;
typedef __attribute__((ext_vector_type(4))) float f32x4;

constexpr int Bn = 4, Sn = 2048, Dn = 1024, Hn = 16, HDn = 64;
constexpr size_t BSD = (size_t)Bn * Sn * Dn;     // 8,388,608
constexpr size_t DD  = (size_t)Dn * Dn;          // 1,048,576

__device__ __forceinline__ u16 f2b(float f) {
    union { bf16 h; u16 u; } c; c.h = __float2bfloat16(f); return c.u;
}

__device__ __forceinline__ bf16x8 cvt_bf8(f32x4 lo, f32x4 hi) {
    union { ushort8_t u; bf16x8 b; } c;
    c.u[0] = f2b(lo[0]); c.u[1] = f2b(lo[1]); c.u[2] = f2b(lo[2]); c.u[3] = f2b(lo[3]);
    c.u[4] = f2b(hi[0]); c.u[5] = f2b(hi[1]); c.u[6] = f2b(hi[2]); c.u[7] = f2b(hi[3]);
    return c.b;
}

// async global->LDS, 16B per lane. LDS dest = wave-uniform base + lane*16.
__device__ __forceinline__ void gl_lds16(const void* g, void* l) {
    __builtin_amdgcn_global_load_lds(
        (const __attribute__((address_space(1))) uint32_t*)g,
        (__attribute__((address_space(3))) uint32_t*)l, 16, 0, 0);
}

// ---------------------------------------------------------------------------
// W[K][N] fp32 -> Wt[N][K] bf16, 32x32 tiles. (unchanged)
// ---------------------------------------------------------------------------
__global__ __launch_bounds__(256) void transpose_w(
    const float* __restrict__ S0, const float* __restrict__ S1, const float* __restrict__ S2,
    u16* __restrict__ D0, u16* __restrict__ D1, u16* __restrict__ D2)
{
    __shared__ u16 tl[32][33];
    const int z = blockIdx.z;
    const float* S = (z == 0) ? S0 : ((z == 1) ? S1 : S2);
    u16*         D = (z == 0) ? D0 : ((z == 1) ? D1 : D2);
    const int k0 = blockIdx.y * 32, n0 = blockIdx.x * 32;
    const int t = threadIdx.x;
    const int r = t >> 3, c0 = (t & 7) * 4;
    float4 v = *(const float4*)(S + (size_t)(k0 + r) * Dn + n0 + c0);
    tl[r][c0] = f2b(v.x); tl[r][c0 + 1] = f2b(v.y);
    tl[r][c0 + 2] = f2b(v.z); tl[r][c0 + 3] = f2b(v.w);
    __syncthreads();
    ushort4 o;
    o.x = tl[c0][r]; o.y = tl[c0 + 1][r]; o.z = tl[c0 + 2][r]; o.w = tl[c0 + 3][r];
    *(ushort4*)(D + (size_t)(n0 + r) * Dn + k0 + c0) = o;
}

// ---------------------------------------------------------------------------
// QKV GEMM (r9 config, unchanged): dbuf, ds_read-first ordering.
// ---------------------------------------------------------------------------
__global__ __launch_bounds__(256) void gemm_qkv(
    const float* __restrict__ A0, const float* __restrict__ A1, const float* __restrict__ A2,
    const u16* __restrict__ B0, const u16* __restrict__ B1, const u16* __restrict__ B2,
    u16* __restrict__ C0, u16* __restrict__ C1, u16* __restrict__ C2, float qscale)
{
    constexpr int K = Dn, BK = 32, BM = 128, NT = K / BK;
    const int z = blockIdx.z;
    const float* A  = (z == 0) ? A0 : ((z == 1) ? A1 : A2);
    const u16*   Bt = (z == 0) ? B0 : ((z == 1) ? B1 : B2);
    u16*         C  = (z == 0) ? C0 : ((z == 1) ? C1 : C2);
    const float scale = (z == 0) ? qscale : 1.0f;

    __shared__ __attribute__((aligned(16))) float As32[2][BM][BK];  // 32 KB
    __shared__ __attribute__((aligned(16))) u16   Bs[2][BM][BK];    // 16 KB

    const int t = threadIdx.x, l = t & 63, w = t >> 6;
    const int i = l & 15, j = l >> 4;

    const int wl   = blockIdx.x * 64 + blockIdx.y;
    const int col0 = (wl & 7) * BM;
    const int row0 = (wl >> 3) * BM;
    const int m_off = (w & 1) * 64, n_off = (w >> 1) * 64;

    const size_t a_base = (size_t)(row0 + w * 32 + (l >> 3)) * K
                          + (size_t)(((l & 7) ^ (l >> 3)) * 4);
    const size_t b_base = (size_t)(col0 + w * 32 + (l >> 2)) * K
                          + (size_t)((l & 3) * 8);

    auto stage = [&](int buf, int kk) {
        float* al = &As32[buf][w * 32][0];
        u16*   bl = &Bs[buf][w * 32][0];
        #pragma unroll
        for (int c = 0; c < 4; c++)
            gl_lds16(A + a_base + (size_t)c * 8 * K + kk, al + c * 8 * BK);
        #pragma unroll
        for (int c = 0; c < 2; c++)
            gl_lds16(Bt + b_base + (size_t)c * 16 * K + kk, bl + c * 16 * BK);
    };

    f32x4 acc[4][4] = {};

    stage(0, 0);
    __syncthreads();

    #pragma unroll 2
    for (int kt = 0; kt < NT; kt++) {
        const int cur = kt & 1;

        f32x4 alo[4], ahi[4];
        bf16x8 bfr[4];
        const int xa = i & 7;
        #pragma unroll
        for (int mi = 0; mi < 4; mi++) {
            const float* rp = &As32[cur][m_off + mi * 16 + i][0];
            alo[mi] = *(const f32x4*)(rp + ((2 * j)     ^ xa) * 4);
            ahi[mi] = *(const f32x4*)(rp + ((2 * j + 1) ^ xa) * 4);
        }
        #pragma unroll
        for (int ni = 0; ni < 4; ni++)
            bfr[ni] = *(const bf16x8*)&Bs[cur][n_off + ni * 16 + i][j * 8];

        if (kt + 1 < NT) stage(cur ^ 1, (kt + 1) * BK);

        bf16x8 af[4];
        #pragma unroll
        for (int mi = 0; mi < 4; mi++)
            af[mi] = cvt_bf8(alo[mi], ahi[mi]);
        #pragma unroll
        for (int mi = 0; mi < 4; mi++)
            #pragma unroll
            for (int ni = 0; ni < 4; ni++)
                acc[mi][ni] = __builtin_amdgcn_mfma_f32_16x16x32_bf16(
                    af[mi], bfr[ni], acc[mi][ni], 0, 0, 0);

        __syncthreads();
    }

    #pragma unroll
    for (int mi = 0; mi < 4; mi++) {
        #pragma unroll
        for (int r = 0; r < 4; r++) {
            const int m = row0 + m_off + mi * 16 + j * 4 + r;
            const int b = m >> 11, s = m & (Sn - 1);
            #pragma unroll
            for (int ni = 0; ni < 4; ni++) {
                const int n = col0 + n_off + ni * 16 + i;
                const int h = n >> 6, hd = n & (HDn - 1);
                C[(((size_t)(b * Hn + h)) * Sn + s) * HDn + hd] = f2b(acc[mi][ni][r] * scale);
            }
        }
    }
}

// ---------------------------------------------------------------------------
// Output GEMM (r9 config, unchanged): dbuf, ds_read-first.
// ---------------------------------------------------------------------------
__global__ __launch_bounds__(256) void gemm_out(
    const u16* __restrict__ A, const u16* __restrict__ Bt, float* __restrict__ C)
{
    constexpr int K = Dn, BK = 32, BM = 128, NT = K / BK;
    __shared__ __attribute__((aligned(16))) u16 As[2][BM][BK];   // 16 KB
    __shared__ __attribute__((aligned(16))) u16 Bs[2][BM][BK];   // 16 KB

    const int t = threadIdx.x, l = t & 63, w = t >> 6;
    const int i = l & 15, j = l >> 4;
    const int wl   = blockIdx.x * 64 + blockIdx.y;
    const int col0 = (wl & 7) * BM;
    const int row0 = (wl >> 3) * BM;
    const int m_off = (w & 1) * 64, n_off = (w >> 1) * 64;

    const size_t a_base = (size_t)(row0 + w * 32 + (l >> 2)) * K + (size_t)((l & 3) * 8);
    const size_t b_base = (size_t)(col0 + w * 32 + (l >> 2)) * K + (size_t)((l & 3) * 8);

    auto stage = [&](int buf, int kk) {
        u16* al = &As[buf][w * 32][0];
        u16* bl = &Bs[buf][w * 32][0];
        #pragma unroll
        for (int c = 0; c < 2; c++)
            gl_lds16(A + a_base + (size_t)c * 16 * K + kk, al + c * 16 * BK);
        #pragma unroll
        for (int c = 0; c < 2; c++)
            gl_lds16(Bt + b_base + (size_t)c * 16 * K + kk, bl + c * 16 * BK);
    };

    f32x4 acc[4][4] = {};

    stage(0, 0);
    __syncthreads();

    #pragma unroll 2
    for (int kt = 0; kt < NT; kt++) {
        const int cur = kt & 1;

        bf16x8 af[4], bfr[4];
        #pragma unroll
        for (int mi = 0; mi < 4; mi++)
            af[mi] = *(const bf16x8*)&As[cur][m_off + mi * 16 + i][j * 8];
        #pragma unroll
        for (int ni = 0; ni < 4; ni++)
            bfr[ni] = *(const bf16x8*)&Bs[cur][n_off + ni * 16 + i][j * 8];

        if (kt + 1 < NT) stage(cur ^ 1, (kt + 1) * BK);

        #pragma unroll
        for (int mi = 0; mi < 4; mi++)
            #pragma unroll
            for (int ni = 0; ni < 4; ni++)
                acc[mi][ni] = __builtin_amdgcn_mfma_f32_16x16x32_bf16(
                    af[mi], bfr[ni], acc[mi][ni], 0, 0, 0);

        __syncthreads();
    }

    #pragma unroll
    for (int mi = 0; mi < 4; mi++) {
        #pragma unroll
        for (int r = 0; r < 4; r++) {
            const int m = row0 + m_off + mi * 16 + j * 4 + r;
            #pragma unroll
            for (int ni = 0; ni < 4; ni++) {
                const int n = col0 + n_off + ni * 16 + i;
                C[(size_t)m * Dn + n] = acc[mi][ni][r];
            }
        }
    }
}

// ---------------------------------------------------------------------------
// MFMA flash attention (r9 structure: TQ=128, 8 waves, Ks/Vt/Ps in LDS).
// ONLY change vs r9: V-transpose staging = one (d,chunk) cell per thread,
// 8 coalesced u16 global reads + ONE ushort8 LDS write.
// ---------------------------------------------------------------------------
__global__ __launch_bounds__(512) void attn_mfma(
    const u16* __restrict__ Qh, const u16* __restrict__ Kh, const u16* __restrict__ Vh,
    const int* __restrict__ vlen, u16* __restrict__ Out)
{
    constexpr int TQ = 128, TK = 64;
    __shared__ __attribute__((aligned(16))) u16 Ks[TK][HDn + 8];   // [64][72]
    __shared__ __attribute__((aligned(16))) u16 Vt[HDn][TK + 8];   // [64][72] d-major
    __shared__ __attribute__((aligned(16))) u16 Ps[TQ][TK + 8];    // [128][72]

    const int t = threadIdx.x, l = t & 63, w = t >> 6;   // w in [0,8)
    const int i = l & 15, j = l >> 4;

    const int b    = blockIdx.x & 3;            // interleave batches (vl imbalance)
    const int rest = blockIdx.x >> 2;
    const int h    = rest & 15;
    const int qt   = rest >> 4;
    const int q0   = qt * TQ;
    const int vl   = vlen[b];

    const size_t hoff = ((size_t)(b * Hn + h)) * Sn * HDn;
    const u16* Qg = Qh + hoff + (size_t)q0 * HDn;
    const u16* Kg = Kh + hoff;
    const u16* Vg = Vh + hoff;

    bf16x8 qf[2];
    #pragma unroll
    for (int ks = 0; ks < 2; ks++)
        qf[ks] = *(const bf16x8*)(Qg + (size_t)(w * 16 + i) * HDn + ks * 32 + j * 8);

    f32x4 acc_o[4] = {};
    float l_part[4] = {0.f, 0.f, 0.f, 0.f};

    const int ntiles = (vl + TK - 1) / TK;

    for (int kt = 0; kt < ntiles; kt++) {
        const int ks0 = kt * TK;
        __syncthreads();
        {   // stage K tile [64][64]: 512 thr x 8 elems, 16B coalesced
            const int kr = t >> 3, kc = (t & 7) * 8;
            *(ushort8_t*)&Ks[kr][kc] =
                *(const ushort8_t*)(Kg + (size_t)(ks0 + kr) * HDn + kc);
        }
        {   // stage V transposed: thread owns (d = t&63, chunk = t>>6).
            // Per kk, a wave reads one contiguous 128B V row (coalesced,
            // L2-hot); one ushort8 LDS write per thread.
            const int d = t & 63, ch = t >> 6;   // ch in [0,8)
            ushort8_t vv;
            #pragma unroll
            for (int kk = 0; kk < 8; kk++)
                vv[kk] = Vg[(size_t)(ks0 + ch * 8 + kk) * HDn + d];
            *(ushort8_t*)&Vt[d][ch * 8] = vv;
        }
        __syncthreads();

        // ---- S = Q K^T ----
        f32x4 s[4] = {};
        #pragma unroll
        for (int ks = 0; ks < 2; ks++) {
            bf16x8 kf[4];
            #pragma unroll
            for (int ni = 0; ni < 4; ni++)
                kf[ni] = *(const bf16x8*)&Ks[ni * 16 + i][ks * 32 + j * 8];
            #pragma unroll
            for (int ni = 0; ni < 4; ni++)
                s[ni] = __builtin_amdgcn_mfma_f32_16x16x32_bf16(
                    qf[ks], kf[ni], s[ni], 0, 0, 0);
        }

        // ---- p = exp(s) (no max), mask, accumulate l, spill P to LDS ----
        const bool tail = (ks0 + TK > vl);
        #pragma unroll
        for (int ni = 0; ni < 4; ni++) {
            const bool keep = !tail || (ks0 + ni * 16 + i < vl);
            #pragma unroll
            for (int r = 0; r < 4; r++) {
                float p = __expf(s[ni][r]);
                p = keep ? p : 0.0f;
                l_part[r] += p;
                Ps[w * 16 + j * 4 + r][ni * 16 + i] = f2b(p);
            }
        }

        // ---- O += P V ----
        #pragma unroll
        for (int ks = 0; ks < 2; ks++) {
            bf16x8 pa = *(const bf16x8*)&Ps[w * 16 + i][ks * 32 + j * 8];
            bf16x8 vb[4];
            #pragma unroll
            for (int di = 0; di < 4; di++)
                vb[di] = *(const bf16x8*)&Vt[di * 16 + i][ks * 32 + j * 8];
            #pragma unroll
            for (int di = 0; di < 4; di++)
                acc_o[di] = __builtin_amdgcn_mfma_f32_16x16x32_bf16(
                    pa, vb[di], acc_o[di], 0, 0, 0);
        }
    }

    #pragma unroll
    for (int r = 0; r < 4; r++) {
        float v = l_part[r];
        #pragma unroll
        for (int d = 1; d < 16; d <<= 1) v += __shfl_xor(v, d, 64);
        l_part[r] = v;
    }

    #pragma unroll
    for (int r = 0; r < 4; r++) {
        const int q = q0 + w * 16 + j * 4 + r;
        const float inv = 1.0f / l_part[r];
        #pragma unroll
        for (int di = 0; di < 4; di++) {
            const int d = di * 16 + i;
            Out[((size_t)b * Sn + q) * Dn + h * HDn + d] = f2b(acc_o[di][r] * inv);
        }
    }
}

// ===========================================================================
extern "C" void kernel_launch(void* const* d_in, const int* in_sizes, int n_in,
                              void* d_out, int out_size, void* d_ws, size_t ws_size,
                              hipStream_t stream)
{
    const float* xq = (const float*)d_in[0];
    const float* xk = (const float*)d_in[1];
    const float* xv = (const float*)d_in[2];
    const int*   vl = (const int*)d_in[3];
    const float* Wq = (const float*)d_in[4];
    const float* Wk = (const float*)d_in[5];
    const float* Wv = (const float*)d_in[6];
    const float* Wo = (const float*)d_in[7];
    float* out = (float*)d_out;

    // scratch (all bf16): Qh|Kh|Vh|Ao = 4*BSD u16 = 67.1 MB.
    // WtQ/K/V live in the not-yet-written Ao region; WoT in dead Qh.
    u16* Qh = (u16*)d_ws;
    u16* Kh = Qh + BSD;
    u16* Vh = Kh + BSD;
    u16* Ao = Vh + BSD;
    u16* WtQ = Ao;
    u16* WtK = WtQ + DD;
    u16* WtV = WtK + DD;
    u16* WoT = Qh;

    transpose_w<<<dim3(32, 32, 3), 256, 0, stream>>>(Wq, Wk, Wv, WtQ, WtK, WtV);
    gemm_qkv<<<dim3(8, 64, 3), 256, 0, stream>>>(xq, xk, xv, WtQ, WtK, WtV,
                                                 Qh, Kh, Vh, 0.125f);
    attn_mfma<<<dim3(Bn * Hn * (Sn / 128)), 512, 0, stream>>>(Qh, Kh, Vh, vl, Ao);
    transpose_w<<<dim3(32, 32, 1), 256, 0, stream>>>(Wo, Wo, Wo, WoT, WoT, WoT);
    gemm_out<<<dim3(8, 64), 256, 0, stream>>>(Ao, WoT, out);
}